// Round 2
// baseline (291.329 us; speedup 1.0000x reference)
//
#include <hip/hip_runtime.h>

#define B_    16
#define T_IN  512
#define D_    256
#define TM    128          // t-tile per block
#define KI    32           // K-chunk (= MFMA K)
#define AP    40           // A_lds row stride in bf16 units (32 + 8 pad; 80 B = 16B-aligned)
#define BP    40           // B_lds row stride in bf16 units

typedef __attribute__((ext_vector_type(8))) short short8;
typedef __attribute__((ext_vector_type(4))) float f32x4;

__device__ __forceinline__ unsigned short f2bf(float x) {
    unsigned u = __builtin_bit_cast(unsigned, x);
    u += 0x7fff + ((u >> 16) & 1);          // RNE
    return (unsigned short)(u >> 16);
}

// One fused kernel: per-block duration scan -> centers; w2 sums; w write; MFMA einsum.
// grid = (ceil(t_out/TM), B). NO d_ws usage (round-1 failure: OOB scratch write
// corrupted the harness's pristine input copies).
__global__ __launch_bounds__(256, 2) void fused_kernel(
    const float* __restrict__ enc,   // [B, T_IN, D]
    const int*   __restrict__ dur,   // [B, T_IN]
    float* __restrict__ out,         // [B, t_out, D]
    float* __restrict__ wout,        // [B, T_IN, t_out]
    int t_out)
{
    __shared__ int   sd[T_IN];
    __shared__ float sc[T_IN];
    __shared__ float sinv[TM];
    __shared__ float red[TM];
    __shared__ __align__(16) unsigned short A_lds[TM * AP];  // w1 bf16, [t][k]
    __shared__ __align__(16) unsigned short B_lds[D_ * BP];  // enc bf16, [d][k]

    const int tid = threadIdx.x;
    const int b   = blockIdx.y;
    const int t0  = blockIdx.x * TM;

    // ---- phase 0: inclusive scan of duration -> centers c = cumsum - 0.5*d ----
    const int v0 = dur[b * T_IN + tid];
    const int v1 = dur[b * T_IN + tid + 256];
    sd[tid] = v0;
    sd[tid + 256] = v1;
    __syncthreads();
    for (int off = 1; off < T_IN; off <<= 1) {
        const int a0 = (tid >= off) ? sd[tid - off] : 0;
        const int a1 = sd[tid + 256 - off];              // tid+256 >= off always (off<=256)
        __syncthreads();
        sd[tid] += a0;
        sd[tid + 256] += a1;
        __syncthreads();
    }
    sc[tid]       = (float)sd[tid]       - 0.5f * (float)v0;
    sc[tid + 256] = (float)sd[tid + 256] - 0.5f * (float)v1;
    __syncthreads();

    // ---- phase 1: w2[t] = sum_i exp(-0.1 (t-c_i)^2), sinv = 1/w2 ----
    const int tl   = tid & 127;          // local t
    const int half = tid >> 7;           // i-half
    const float tv = (float)(t0 + tl + 1);
    {
        float s = 0.f;
        const int i0 = half * 256;
        for (int i = 0; i < 256; ++i) {
            const float d = tv - sc[i0 + i];
            s += __expf(-0.1f * d * d);
        }
        if (half == 0) red[tl] = s;
        __syncthreads();
        if (half == 1) red[tl] += s;
        __syncthreads();
        if (half == 0) {
            const float w2 = red[tl];
            sinv[tl] = (w2 == 0.f) ? 1.f : 1.f / w2;
        }
        __syncthreads();
    }

    // ---- phase W: write w[b,i,t] = w1 * inv (fp32, coalesced over t) ----
    if (t0 + tl < t_out) {
        const float inv = sinv[tl];
        const int i0 = half * 256;
        float* wp = wout + ((long long)b * T_IN + i0) * t_out + (t0 + tl);
        for (int i = 0; i < 256; ++i) {
            const float d = tv - sc[i0 + i];
            wp[(long long)i * t_out] = __expf(-0.1f * d * d) * inv;
        }
    }

    // ---- phase M: MFMA einsum, out[t, d] = inv[t] * sum_i w1[i,t] * enc[i,d] ----
    const int lane = tid & 63;
    const int wave = tid >> 6;
    const int wm   = wave & 1;    // t-offset 64*wm
    const int wn   = wave >> 1;   // d-offset 128*wn
    const int mrow = lane & 15;
    const int quad = lane >> 4;

    f32x4 acc[4][8];
    #pragma unroll
    for (int mf = 0; mf < 4; ++mf)
        #pragma unroll
        for (int nf = 0; nf < 8; ++nf)
            acc[mf][nf] = (f32x4){0.f, 0.f, 0.f, 0.f};

    for (int kc = 0; kc < T_IN; kc += KI) {
        __syncthreads();   // previous iter's frag reads done before re-staging

        // stage A: w1[t][k] bf16. thread -> t_loc = tid&127, 16 consecutive i.
        {
            const int t_loc = tid & 127;
            const int i0    = (tid >> 7) * 16;
            const float tvs = (float)(t0 + t_loc + 1);
            unsigned short tmp[16];
            #pragma unroll
            for (int j = 0; j < 16; ++j) {
                const float d = tvs - sc[kc + i0 + j];
                tmp[j] = f2bf(__expf(-0.1f * d * d));
            }
            *(short8*)&A_lds[t_loc * AP + i0]     = *(const short8*)&tmp[0];
            *(short8*)&A_lds[t_loc * AP + i0 + 8] = *(const short8*)&tmp[8];
        }
        // stage B: enc[i][d] fp32 -> bf16 transposed [d][k]. coalesced float4 reads.
        {
            const int dq = (lane) * 4;         // 0..252 per wave
            #pragma unroll
            for (int p = 0; p < 8; ++p) {
                const int il = wave + p * 4;   // 0..31
                const float4 ev = *(const float4*)&enc[((long long)b * T_IN + kc + il) * D_ + dq];
                B_lds[(dq + 0) * BP + il] = f2bf(ev.x);
                B_lds[(dq + 1) * BP + il] = f2bf(ev.y);
                B_lds[(dq + 2) * BP + il] = f2bf(ev.z);
                B_lds[(dq + 3) * BP + il] = f2bf(ev.w);
            }
        }
        __syncthreads();

        // MFMA: wave tile 64 t x 128 d = 4 m-frags x 8 n-frags
        short8 av[4];
        #pragma unroll
        for (int mf = 0; mf < 4; ++mf)
            av[mf] = *(const short8*)&A_lds[(wm * 64 + mf * 16 + mrow) * AP + quad * 8];
        #pragma unroll
        for (int nf = 0; nf < 8; ++nf) {
            const short8 bv = *(const short8*)&B_lds[(wn * 128 + nf * 16 + mrow) * BP + quad * 8];
            #pragma unroll
            for (int mf = 0; mf < 4; ++mf)
                acc[mf][nf] = __builtin_amdgcn_mfma_f32_16x16x32_bf16(av[mf], bv, acc[mf][nf], 0, 0, 0);
        }
    }

    // ---- epilogue: out = acc * inv[t]. C/D layout: col=lane&15, row=quad*4+reg ----
    #pragma unroll
    for (int mf = 0; mf < 4; ++mf) {
        #pragma unroll
        for (int r = 0; r < 4; ++r) {
            const int tloc = wm * 64 + mf * 16 + quad * 4 + r;
            const int t = t0 + tloc;
            if (t < t_out) {
                const float inv = sinv[tloc];
                #pragma unroll
                for (int nf = 0; nf < 8; ++nf) {
                    const int d = wn * 128 + nf * 16 + mrow;
                    out[((long long)b * t_out + t) * D_ + d] = acc[mf][nf][r] * inv;
                }
            }
        }
    }
}

extern "C" void kernel_launch(void* const* d_in, const int* in_sizes, int n_in,
                              void* d_out, int out_size, void* d_ws, size_t ws_size,
                              hipStream_t stream) {
    const float* enc = (const float*)d_in[0];
    const int*   dur = (const int*)d_in[1];
    // d_in[2] = mask, all-true, unused by the math

    const int t_out = out_size / (B_ * (D_ + T_IN));   // out_size = B*t_out*D + B*T_IN*t_out

    float* out  = (float*)d_out;
    float* wout = (float*)d_out + (size_t)B_ * t_out * D_;

    dim3 grid((t_out + TM - 1) / TM, B_);
    fused_kernel<<<grid, 256, 0, stream>>>(enc, dur, out, wout, t_out);
}

// Round 3
// 260.886 us; speedup vs baseline: 1.1167x; 1.1167x over previous
//
#include <hip/hip_runtime.h>

#define B_    16
#define T_IN  512
#define D_    256
#define TM    64           // t-tile per block (64 -> 992 blocks, ~4/CU)
#define KI    32           // K-chunk (= MFMA K)
#define AP    40           // A_lds row stride in bf16 units (32 + 8 pad, 16B-aligned rows)

typedef __attribute__((ext_vector_type(8))) short short8;
typedef __attribute__((ext_vector_type(4))) float f32x4;

__device__ __forceinline__ unsigned short f2bf(float x) {
    unsigned u = __builtin_bit_cast(unsigned, x);
    u += 0x7fff + ((u >> 16) & 1);          // RNE
    return (unsigned short)(u >> 16);
}

// Fully fused: duration scan -> centers; w2 sums; k-loop {w-write + A-stage + MFMA}.
// B operand (enc) is loaded DIRECTLY global->fragment (R2 post-mortem: any bf16
// [d][k] LDS transpose tile with 16B rows is >=8-way write-conflicted; 3.3e7
// conflict cycles = 39% of runtime). enc stays L2-resident (512 KB/batch).
// No d_ws usage (R1: OOB scratch write corrupted harness pristine inputs).
__global__ __launch_bounds__(256, 3) void fused_kernel(
    const float* __restrict__ enc,   // [B, T_IN, D]
    const int*   __restrict__ dur,   // [B, T_IN]
    float* __restrict__ out,         // [B, t_out, D]
    float* __restrict__ wout,        // [B, T_IN, t_out]
    int t_out)
{
    __shared__ int   sd[T_IN];
    __shared__ float sc[T_IN];
    __shared__ float red[4][TM];
    __shared__ float sinv[TM];
    __shared__ __align__(16) unsigned short A_lds[TM * AP];   // 5 KB

    const int tid = threadIdx.x;
    const int b   = blockIdx.y;
    const int t0  = blockIdx.x * TM;

    // ---- phase 0: inclusive scan of duration -> centers c = cumsum - 0.5*d ----
    const int v0 = dur[b * T_IN + tid];
    const int v1 = dur[b * T_IN + tid + 256];
    sd[tid] = v0;
    sd[tid + 256] = v1;
    __syncthreads();
    for (int off = 1; off < T_IN; off <<= 1) {
        const int a0 = (tid >= off) ? sd[tid - off] : 0;
        const int a1 = sd[tid + 256 - off];              // tid+256 >= off always
        __syncthreads();
        sd[tid] += a0;
        sd[tid + 256] += a1;
        __syncthreads();
    }
    sc[tid]       = (float)sd[tid]       - 0.5f * (float)v0;
    sc[tid + 256] = (float)sd[tid + 256] - 0.5f * (float)v1;
    __syncthreads();

    const int tq = tid & 63;     // this thread's t (same for all 4 waves)
    const int qq = tid >> 6;     // wave index = i-quarter
    const float tv = (float)(t0 + tq + 1);

    // ---- phase 1: w2[t] = sum_i exp(-0.1 (t-c_i)^2); sinv = 1/w2 ----
    {
        float s = 0.f;
        const int i0 = qq * 128;
        for (int i = 0; i < 128; ++i) {
            const float d = tv - sc[i0 + i];
            s += __expf(-0.1f * d * d);
        }
        red[qq][tq] = s;
        __syncthreads();
        if (qq == 0) {
            const float w2 = red[0][tq] + red[1][tq] + red[2][tq] + red[3][tq];
            sinv[tq] = (w2 == 0.f) ? 1.f : 1.f / w2;
        }
        __syncthreads();
    }
    const float inv_t = sinv[tq];
    const bool  t_ok  = (t0 + tq) < t_out;

    // ---- k-loop: per 32-k chunk: {w-write + bf16 A-stage} then MFMA with direct-global B ----
    const int lane  = tid & 63;
    const int wave  = tid >> 6;
    const int mrow  = lane & 15;
    const int quad  = lane >> 4;
    const int dbase = wave * 64;     // each wave owns a distinct 64-d slice (no B redundancy)
    const int iq0   = qq * 8;        // thread's 8 consecutive i within the chunk

    f32x4 acc[4][4];
    #pragma unroll
    for (int mf = 0; mf < 4; ++mf)
        #pragma unroll
        for (int nf = 0; nf < 4; ++nf)
            acc[mf][nf] = (f32x4){0.f, 0.f, 0.f, 0.f};

    const float* encB = enc + (long long)b * T_IN * D_;
    float* wB = wout + (long long)b * T_IN * t_out + (t0 + tq);

    for (int kc = 0; kc < T_IN; kc += KI) {
        __syncthreads();   // previous iteration's A-frag reads done before restage

        // stage A (bf16 [t][k] tile) + write w = w1 * inv (coalesced over t, 256B/instr)
        {
            unsigned short tmp[8];
            #pragma unroll
            for (int j = 0; j < 8; ++j) {
                const float d = tv - sc[kc + iq0 + j];
                const float e = __expf(-0.1f * d * d);
                tmp[j] = f2bf(e);
                if (t_ok) wB[(long long)(kc + iq0 + j) * t_out] = e * inv_t;
            }
            *(short8*)&A_lds[tq * AP + iq0] = *(const short8*)tmp;
        }
        __syncthreads();

        // A fragments from LDS
        short8 av[4];
        #pragma unroll
        for (int mf = 0; mf < 4; ++mf)
            av[mf] = *(const short8*)&A_lds[(mf * 16 + mrow) * AP + quad * 8];

        // B fragments direct from global (L2-hot): lane -> enc[kc+quad*8+j][dbase+nf*16+mrow]
        #pragma unroll
        for (int nf = 0; nf < 4; ++nf) {
            const float* p = encB + (long long)(kc + quad * 8) * D_ + dbase + nf * 16 + mrow;
            unsigned short bt[8];
            #pragma unroll
            for (int j = 0; j < 8; ++j) bt[j] = f2bf(p[j * D_]);
            const short8 bv = *(const short8*)bt;
            #pragma unroll
            for (int mf = 0; mf < 4; ++mf)
                acc[mf][nf] = __builtin_amdgcn_mfma_f32_16x16x32_bf16(av[mf], bv, acc[mf][nf], 0, 0, 0);
        }
    }

    // ---- epilogue: out = acc * inv[t]. C/D layout: col=lane&15, row=quad*4+reg ----
    #pragma unroll
    for (int mf = 0; mf < 4; ++mf) {
        #pragma unroll
        for (int r = 0; r < 4; ++r) {
            const int tl = mf * 16 + quad * 4 + r;
            const int t  = t0 + tl;
            if (t < t_out) {
                const float inv = sinv[tl];
                #pragma unroll
                for (int nf = 0; nf < 4; ++nf)
                    out[((long long)b * t_out + t) * D_ + dbase + nf * 16 + mrow] = acc[mf][nf][r] * inv;
            }
        }
    }
}

extern "C" void kernel_launch(void* const* d_in, const int* in_sizes, int n_in,
                              void* d_out, int out_size, void* d_ws, size_t ws_size,
                              hipStream_t stream) {
    const float* enc = (const float*)d_in[0];
    const int*   dur = (const int*)d_in[1];
    // d_in[2] = mask, all-true, unused by the math

    const int t_out = out_size / (B_ * (D_ + T_IN));   // out_size = B*t_out*D + B*T_IN*t_out

    float* out  = (float*)d_out;
    float* wout = (float*)d_out + (size_t)B_ * t_out * D_;

    dim3 grid((t_out + TM - 1) / TM, B_);
    fused_kernel<<<grid, 256, 0, stream>>>(enc, dur, out, wout, t_out);
}